// Round 10
// baseline (651.189 us; speedup 1.0000x reference)
//
#include <hip/hip_runtime.h>

#define N_NODES 100000
#define N_PAD 100032   // divisible by 32 and 64
#define N_EDGES 1600000
#define DIM 128
#define N_GRAPHS 1024

#define SCAN_BLOCK 256
#define SCAN_NB ((N_NODES + SCAN_BLOCK - 1) / SCAN_BLOCK)  // 391

#define NPART 4
#define PART_SZ 25000

#define TROWS 32                 // tile rows per block (R9: 64 -> grid-undersubscribed)

typedef __bf16 bf16x8 __attribute__((ext_vector_type(8)));
typedef float f32x4 __attribute__((ext_vector_type(4)));

__device__ __forceinline__ unsigned short f2bf(float f) {
    unsigned u = __builtin_bit_cast(unsigned, f);
    u += 0x7fffu + ((u >> 16) & 1u);  // RNE
    return (unsigned short)(u >> 16);
}
__device__ __forceinline__ unsigned pk2(float a, float b) {
    return (unsigned)f2bf(a) | ((unsigned)f2bf(b) << 16);
}
__device__ __forceinline__ float bf2f(unsigned short s) {
    return __builtin_bit_cast(float, (unsigned)s << 16);
}
__device__ __forceinline__ void dec2(unsigned p, float& lo, float& hi) {
    lo = __builtin_bit_cast(float, p << 16);
    hi = __builtin_bit_cast(float, p & 0xffff0000u);
}

template <bool BN>
__device__ __forceinline__ void acc8(uint4 p, float* a, const float* sc, const float* sh) {
    float v[8];
    dec2(p.x, v[0], v[1]);
    dec2(p.y, v[2], v[3]);
    dec2(p.z, v[4], v[5]);
    dec2(p.w, v[6], v[7]);
#pragma unroll
    for (int j = 0; j < 8; ++j) {
        float t = BN ? fmaxf(fmaf(v[j], sc[j], sh[j]), 0.f) : v[j];
        a[j] += t;
    }
}

// ---------------- CSR build ----------------

__global__ __launch_bounds__(256) void hist_kernel(const int* __restrict__ dst,
                                                   int* __restrict__ deg) {
    int i = blockIdx.x * blockDim.x + threadIdx.x;
    int stride = gridDim.x * blockDim.x;
    const int NE4 = N_EDGES / 4;
    for (; i < NE4; i += stride) {
        int4 d4 = ((const int4*)dst)[i];
        atomicAdd(&deg[d4.x], 1);
        atomicAdd(&deg[d4.y], 1);
        atomicAdd(&deg[d4.z], 1);
        atomicAdd(&deg[d4.w], 1);
    }
}

// fill partitioned by dst range (4 partitions x 2 XCDs: 2x write-amp vs 16x
// unpartitioned, half the edge-list re-reads vs NPART=8)
__global__ __launch_bounds__(256) void fill_part_kernel(const int* __restrict__ src,
                                                        const int* __restrict__ dst,
                                                        int* __restrict__ cursor,
                                                        int* __restrict__ csr) {
    int p = blockIdx.x & (NPART - 1);
    int bgrp = blockIdx.x >> 2;
    int nb = gridDim.x >> 2;
    int tid = bgrp * blockDim.x + threadIdx.x;
    int nthreads = nb * blockDim.x;
    const int NE8 = N_EDGES / 8;
    for (int i = tid; i < NE8; i += nthreads) {
        int4 da = ((const int4*)dst)[2 * i];
        int4 db = ((const int4*)dst)[2 * i + 1];
        int4 sa = ((const int4*)src)[2 * i];
        int4 sb = ((const int4*)src)[2 * i + 1];
        if (da.x / PART_SZ == p) csr[atomicAdd(&cursor[da.x], 1)] = sa.x;
        if (da.y / PART_SZ == p) csr[atomicAdd(&cursor[da.y], 1)] = sa.y;
        if (da.z / PART_SZ == p) csr[atomicAdd(&cursor[da.z], 1)] = sa.z;
        if (da.w / PART_SZ == p) csr[atomicAdd(&cursor[da.w], 1)] = sa.w;
        if (db.x / PART_SZ == p) csr[atomicAdd(&cursor[db.x], 1)] = sb.x;
        if (db.y / PART_SZ == p) csr[atomicAdd(&cursor[db.y], 1)] = sb.y;
        if (db.z / PART_SZ == p) csr[atomicAdd(&cursor[db.z], 1)] = sb.z;
        if (db.w / PART_SZ == p) csr[atomicAdd(&cursor[db.w], 1)] = sb.w;
    }
}

// ---------------- hierarchical scan ----------------

__global__ __launch_bounds__(SCAN_BLOCK) void scan_partial_kernel(const int* __restrict__ deg,
                                                                  int* __restrict__ partials) {
    __shared__ int red[SCAN_BLOCK / 64];
    int i = blockIdx.x * SCAN_BLOCK + threadIdx.x;
    int v = (i < N_NODES) ? deg[i] : 0;
    for (int o = 32; o > 0; o >>= 1) v += __shfl_down(v, o, 64);
    if ((threadIdx.x & 63) == 0) red[threadIdx.x >> 6] = v;
    __syncthreads();
    if (threadIdx.x == 0) {
        int s = 0;
#pragma unroll
        for (int w = 0; w < SCAN_BLOCK / 64; ++w) s += red[w];
        partials[blockIdx.x] = s;
    }
}

__global__ __launch_bounds__(512) void scan_partials_kernel(int* __restrict__ partials,
                                                            int* __restrict__ off) {
    __shared__ int sm[512];
    int t = threadIdx.x;
    int v = (t < SCAN_NB) ? partials[t] : 0;
    sm[t] = v;
    __syncthreads();
    for (int o = 1; o < 512; o <<= 1) {
        int u = (t >= o) ? sm[t - o] : 0;
        __syncthreads();
        sm[t] += u;
        __syncthreads();
    }
    if (t < SCAN_NB) partials[t] = sm[t] - v;
    if (t == 0) off[N_NODES] = sm[511];
}

__global__ __launch_bounds__(SCAN_BLOCK) void scan_scatter_kernel(const int* __restrict__ deg,
                                                                  const int* __restrict__ partials,
                                                                  int* __restrict__ off,
                                                                  int* __restrict__ cursor) {
    __shared__ int sm[SCAN_BLOCK];
    int t = threadIdx.x;
    int i = blockIdx.x * SCAN_BLOCK + t;
    int v = (i < N_NODES) ? deg[i] : 0;
    sm[t] = v;
    __syncthreads();
    for (int o = 1; o < SCAN_BLOCK; o <<= 1) {
        int u = (t >= o) ? sm[t - o] : 0;
        __syncthreads();
        sm[t] += u;
        __syncthreads();
    }
    if (i < N_NODES) {
        int r = partials[blockIdx.x] + sm[t] - v;
        off[i] = r;
        cursor[i] = r;
    }
}

// ---------------- W -> bf16 B-fragment layout (verified R5) ----------------

__global__ __launch_bounds__(64) void wprep_kernel(const float* __restrict__ W1,
                                                   const float* __restrict__ W2,
                                                   const float* __restrict__ W3,
                                                   uint4* __restrict__ wb4) {
    int b = blockIdx.x;           // l*32 + nt*4 + kk
    int l = b >> 5;
    int nt = (b >> 2) & 7;
    int kk = b & 3;
    int lane = threadIdx.x;
    const float* W = (l == 0) ? W1 : (l == 1) ? W2 : W3;
    int row = nt * 16 + (lane & 15);
    int cb = kk * 32 + (lane >> 4) * 8;
    const float* g = W + row * DIM + cb;
    float4 f0 = *(const float4*)g;
    float4 f1 = *(const float4*)(g + 4);
    uint4 o;
    o.x = pk2(f0.x, f0.y);
    o.y = pk2(f0.z, f0.w);
    o.z = pk2(f1.x, f1.y);
    o.w = pk2(f1.z, f1.w);
    wb4[(size_t)b * 64 + lane] = o;
}

// ---------------- x f32 -> bf16 (padded rows zeroed) ----------------

__global__ __launch_bounds__(256) void xconv_kernel(const float* __restrict__ x,
                                                    unsigned short* __restrict__ xb) {
    int i = blockIdx.x * blockDim.x + threadIdx.x;
    int stride = gridDim.x * blockDim.x;
    const int TOT = N_PAD * DIM / 8;
    for (; i < TOT; i += stride) {
        int row = i >> 4;
        int ks = i & 15;
        uint4 o = {0, 0, 0, 0};
        if (row < N_NODES) {
            const float* g = x + (size_t)row * DIM + ks * 8;
            float4 f0 = *(const float4*)g;
            float4 f1 = *(const float4*)(g + 4);
            o.x = pk2(f0.x, f0.y);
            o.y = pk2(f0.z, f0.w);
            o.z = pk2(f1.x, f1.y);
            o.w = pk2(f1.z, f1.w);
        }
        ((uint4*)xb)[i] = o;
    }
}

// ---------------- fused agg + MFMA GEMM, 32-row tile ----------------
// R9 lesson: grid 1563 blocks = 6/CU undersubscribed the gather phase.
// 32-row tile -> 3126 blocks (~12/CU queued, 8 resident = 32 waves/CU).
// Wave-per-row gather (zero divergence), 4 quads in flight (16 edges/trip).
// MFMA: wave w -> row-tile (w&1), col-group (w>>1), 16 MFMA/wave.

template <bool BN>
__global__ __launch_bounds__(256) void agg_gemm_kernel(const unsigned short* __restrict__ hin,
                                                       const int* __restrict__ off,
                                                       const int* __restrict__ csr,
                                                       const float* __restrict__ eps_arr, int layer,
                                                       const float* __restrict__ csum_prev,
                                                       const float* __restrict__ csq_prev,
                                                       const float* __restrict__ gamma_prev,
                                                       const float* __restrict__ beta_prev,
                                                       const uint4* __restrict__ wb4,
                                                       unsigned short* __restrict__ y,
                                                       float* __restrict__ csum_out,
                                                       float* __restrict__ csq_out) {
    __shared__ unsigned short tile[TROWS * DIM];  // 8 KB, 16B-granular XOR swizzle
    __shared__ float sstat[4][64];
    __shared__ float sstatq[4][64];
    int tid = threadIdx.x;
    int row0 = blockIdx.x * TROWS;
    int wv = tid >> 6;          // wave 0..3, owns rows wv*8 .. wv*8+7
    int esl = (tid >> 4) & 3;   // edge slot
    int dl = tid & 15;          // dim lane: dims dl*8 .. dl*8+7
    float se = 1.0f + eps_arr[layer];
    float sc[8], sh[8];
    if (BN) {
#pragma unroll
        for (int j = 0; j < 8; ++j) {
            int d = dl * 8 + j;
            float m = csum_prev[d] * (1.0f / N_NODES);
            float var = csq_prev[d] * (1.0f / N_NODES) - m * m;
            float s = gamma_prev[d] * rsqrtf(var + 1e-5f);
            sc[j] = s;
            sh[j] = beta_prev[d] - m * s;
        }
    }
    const uint4* base = (const uint4*)hin + dl;
    const size_t RS = DIM / 8;

#pragma unroll 1
    for (int r = 0; r < 8; ++r) {
        int trow = wv * 8 + r;
        int row = row0 + trow;
        float a[8] = {0.f, 0.f, 0.f, 0.f, 0.f, 0.f, 0.f, 0.f};
        float s8[8] = {0.f, 0.f, 0.f, 0.f, 0.f, 0.f, 0.f, 0.f};
        if (row < N_NODES) {
            {   // self term
                uint4 pv = base[(size_t)row * RS];
                float v[8];
                dec2(pv.x, v[0], v[1]); dec2(pv.y, v[2], v[3]);
                dec2(pv.z, v[4], v[5]); dec2(pv.w, v[6], v[7]);
#pragma unroll
                for (int j = 0; j < 8; ++j)
                    s8[j] = BN ? fmaxf(fmaf(v[j], sc[j], sh[j]), 0.f) : v[j];
            }
            int k = off[row], e = off[row + 1];
            // 16 edges/trip: 4 x 1KB wave-gathers in flight
            for (; k + 16 <= e; k += 16) {
                int i0 = csr[k + esl];
                int i1 = csr[k + 4 + esl];
                int i2 = csr[k + 8 + esl];
                int i3 = csr[k + 12 + esl];
                uint4 p0 = base[(size_t)i0 * RS];
                uint4 p1 = base[(size_t)i1 * RS];
                uint4 p2 = base[(size_t)i2 * RS];
                uint4 p3 = base[(size_t)i3 * RS];
                acc8<BN>(p0, a, sc, sh);
                acc8<BN>(p1, a, sc, sh);
                acc8<BN>(p2, a, sc, sh);
                acc8<BN>(p3, a, sc, sh);
            }
            for (; k + 8 <= e; k += 8) {
                int i0 = csr[k + esl];
                int i1 = csr[k + 4 + esl];
                uint4 p0 = base[(size_t)i0 * RS];
                uint4 p1 = base[(size_t)i1 * RS];
                acc8<BN>(p0, a, sc, sh);
                acc8<BN>(p1, a, sc, sh);
            }
            for (; k < e; k += 4) {
                int kk = k + esl;
                if (kk < e) {
                    uint4 p0 = base[(size_t)csr[kk] * RS];
                    acc8<BN>(p0, a, sc, sh);
                }
            }
        }
#pragma unroll
        for (int j = 0; j < 8; ++j) {
            a[j] += __shfl_xor(a[j], 16);
            a[j] += __shfl_xor(a[j], 32);
            a[j] = fmaf(se, s8[j], a[j]);
        }
        if (esl == 0) {
            uint4 pw;
            pw.x = pk2(a[0], a[1]);
            pw.y = pk2(a[2], a[3]);
            pw.z = pk2(a[4], a[5]);
            pw.w = pk2(a[6], a[7]);
            int byte = (trow * 256 + dl * 16) ^ ((trow & 7) << 4);
            *(uint4*)((char*)tile + byte) = pw;
        }
    }
    __syncthreads();

    // ---- MFMA phase: wave w -> row-tile rt=w&1, col-group cg=w>>1 ----
    int w = tid >> 6;
    int l = tid & 63;
    int lr = l & 15;
    int lg = l >> 4;
    int rt = w & 1;
    int cg = w >> 1;
    bf16x8 a[4];
#pragma unroll
    for (int kk = 0; kk < 4; ++kk) {
        int row = rt * 16 + lr;
        int byte = (row * 256 + kk * 64 + lg * 16) ^ ((row & 7) << 4);
        a[kk] = __builtin_bit_cast(bf16x8, *(uint4*)((char*)tile + byte));
    }

#pragma unroll
    for (int ntl = 0; ntl < 4; ++ntl) {
        int nt = cg * 4 + ntl;
        f32x4 acc = {0.0f, 0.0f, 0.0f, 0.0f};
#pragma unroll
        for (int kk = 0; kk < 4; ++kk) {
            bf16x8 b = __builtin_bit_cast(bf16x8, wb4[(nt * 4 + kk) * 64 + l]);
            acc = __builtin_amdgcn_mfma_f32_16x16x32_bf16(a[kk], b, acc, 0, 0, 0);
        }
        int col = nt * 16 + lr;
        size_t base2 = (size_t)(row0 + rt * 16 + lg * 4) * DIM + col;
        y[base2] = f2bf(acc[0]);
        y[base2 + DIM] = f2bf(acc[1]);
        y[base2 + 2 * DIM] = f2bf(acc[2]);
        y[base2 + 3 * DIM] = f2bf(acc[3]);
        float s = acc[0] + acc[1] + acc[2] + acc[3];
        float q = acc[0] * acc[0] + acc[1] * acc[1] + acc[2] * acc[2] + acc[3] * acc[3];
        s += __shfl_xor(s, 16);
        s += __shfl_xor(s, 32);
        q += __shfl_xor(q, 16);
        q += __shfl_xor(q, 32);
        if (lg == 0) {
            sstat[w][col & 63] = s;    // cols within this wave's 64-col group
            sstatq[w][col & 63] = q;
        }
    }
    __syncthreads();
    if (tid < DIM) {
        int cg2 = tid >> 6;
        int c = tid & 63;
        float s = sstat[cg2 * 2][c] + sstat[cg2 * 2 + 1][c];
        float q = sstatq[cg2 * 2][c] + sstatq[cg2 * 2 + 1][c];
        atomicAdd(&csum_out[tid], s);
        atomicAdd(&csq_out[tid], q);
    }
}

// ---------------- global mean pool (final BN+ReLU inline) ----------------

__global__ __launch_bounds__(128) void pool_kernel(const unsigned short* __restrict__ y,
                                                   const int* __restrict__ batch,
                                                   const float* __restrict__ csum,
                                                   const float* __restrict__ csq,
                                                   const float* __restrict__ gamma,
                                                   const float* __restrict__ beta,
                                                   float* __restrict__ out) {
    int gph = blockIdx.x;
    int d = threadIdx.x;
    float m = csum[d] * (1.0f / N_NODES);
    float var = csq[d] * (1.0f / N_NODES) - m * m;
    float sc = gamma[d] * rsqrtf(var + 1e-5f);
    float sh = beta[d] - m * sc;
    int lo = 0, hi = N_NODES;
    while (lo < hi) {
        int mid = (lo + hi) >> 1;
        if (batch[mid] < gph) lo = mid + 1; else hi = mid;
    }
    int start = lo;
    hi = N_NODES;
    while (lo < hi) {
        int mid = (lo + hi) >> 1;
        if (batch[mid] < gph + 1) lo = mid + 1; else hi = mid;
    }
    int end = lo;
    float s0 = 0.f, s1 = 0.f, s2 = 0.f, s3 = 0.f;
    int n = start;
    for (; n + 3 < end; n += 4) {
        float v0 = bf2f(y[(size_t)n * DIM + d]);
        float v1 = bf2f(y[(size_t)(n + 1) * DIM + d]);
        float v2 = bf2f(y[(size_t)(n + 2) * DIM + d]);
        float v3 = bf2f(y[(size_t)(n + 3) * DIM + d]);
        s0 += fmaxf(fmaf(v0, sc, sh), 0.0f);
        s1 += fmaxf(fmaf(v1, sc, sh), 0.0f);
        s2 += fmaxf(fmaf(v2, sc, sh), 0.0f);
        s3 += fmaxf(fmaf(v3, sc, sh), 0.0f);
    }
    for (; n < end; ++n) {
        float v = bf2f(y[(size_t)n * DIM + d]);
        s0 += fmaxf(fmaf(v, sc, sh), 0.0f);
    }
    float s = (s0 + s1) + (s2 + s3);
    out[gph * DIM + d] = s / fmaxf((float)(end - start), 1.0f);
}

// ---------------- launch ----------------

extern "C" void kernel_launch(void* const* d_in, const int* in_sizes, int n_in,
                              void* d_out, int out_size, void* d_ws, size_t ws_size,
                              hipStream_t stream) {
    const float* x = (const float*)d_in[0];
    const int* ei = (const int*)d_in[1];
    const int* batch = (const int*)d_in[2];
    const float* Wp[3] = {(const float*)d_in[3], (const float*)d_in[5], (const float*)d_in[7]};
    const float* eps = (const float*)d_in[9];
    const float* gamma = (const float*)d_in[10];
    const float* beta = (const float*)d_in[11];
    float* out = (float*)d_out;

    char* ws = (char*)d_ws;
    size_t o = 0;
    auto alloc = [&](size_t bytes) {
        void* p = ws + o;
        o = (o + bytes + 255) & ~(size_t)255;
        return p;
    };
    int* deg = (int*)alloc(N_NODES * sizeof(int));
    int* off = (int*)alloc((N_NODES + 1) * sizeof(int));
    int* cursor = (int*)alloc(N_NODES * sizeof(int));
    int* partials = (int*)alloc(SCAN_NB * sizeof(int));
    int* csr = (int*)alloc(N_EDGES * sizeof(int));
    uint4* wb4 = (uint4*)alloc(3 * 8 * 4 * 64 * 16);
    float* csums = (float*)alloc(3 * DIM * sizeof(float));
    float* csqs = (float*)alloc(3 * DIM * sizeof(float));
    unsigned short* xb = (unsigned short*)alloc((size_t)N_PAD * DIM * 2);
    unsigned short* y0 = (unsigned short*)alloc((size_t)N_PAD * DIM * 2);
    unsigned short* y1 = (unsigned short*)alloc((size_t)N_PAD * DIM * 2);

    hipMemsetAsync(deg, 0, N_NODES * sizeof(int), stream);
    hipMemsetAsync(csums, 0, 3 * DIM * sizeof(float), stream);
    hipMemsetAsync(csqs, 0, 3 * DIM * sizeof(float), stream);

    hist_kernel<<<1024, 256, 0, stream>>>(ei + N_EDGES, deg);
    scan_partial_kernel<<<SCAN_NB, SCAN_BLOCK, 0, stream>>>(deg, partials);
    scan_partials_kernel<<<1, 512, 0, stream>>>(partials, off);
    scan_scatter_kernel<<<SCAN_NB, SCAN_BLOCK, 0, stream>>>(deg, partials, off, cursor);
    fill_part_kernel<<<2048, 256, 0, stream>>>(ei, ei + N_EDGES, cursor, csr);
    wprep_kernel<<<96, 64, 0, stream>>>(Wp[0], Wp[1], Wp[2], wb4);
    xconv_kernel<<<2048, 256, 0, stream>>>(x, xb);

    const int NBLK = N_PAD / TROWS;  // 3126
    agg_gemm_kernel<false><<<NBLK, 256, 0, stream>>>(xb, off, csr, eps, 0,
                                                     nullptr, nullptr, nullptr, nullptr,
                                                     wb4, y0, csums, csqs);
    agg_gemm_kernel<true><<<NBLK, 256, 0, stream>>>(y0, off, csr, eps, 1,
                                                    csums, csqs, gamma, beta,
                                                    wb4 + 2048, y1, csums + DIM, csqs + DIM);
    agg_gemm_kernel<true><<<NBLK, 256, 0, stream>>>(y1, off, csr, eps, 2,
                                                    csums + DIM, csqs + DIM, gamma + DIM, beta + DIM,
                                                    wb4 + 4096, y0, csums + 2 * DIM, csqs + 2 * DIM);
    pool_kernel<<<N_GRAPHS, DIM, 0, stream>>>(y0, batch, csums + 2 * DIM, csqs + 2 * DIM,
                                              gamma + 2 * DIM, beta + 2 * DIM, out);
}

// Round 11
// 575.224 us; speedup vs baseline: 1.1321x; 1.1321x over previous
//
#include <hip/hip_runtime.h>

#define N_NODES 100000
#define N_PAD 100032   // 1563 * 64
#define N_EDGES 1600000
#define DIM 128
#define N_GRAPHS 1024

#define SCAN_BLOCK 256
#define SCAN_NB ((N_NODES + SCAN_BLOCK - 1) / SCAN_BLOCK)  // 391

#define NPART 4
#define PART_SZ 25000

typedef __bf16 bf16x8 __attribute__((ext_vector_type(8)));
typedef float f32x4 __attribute__((ext_vector_type(4)));

__device__ __forceinline__ unsigned short f2bf(float f) {
    unsigned u = __builtin_bit_cast(unsigned, f);
    u += 0x7fffu + ((u >> 16) & 1u);  // RNE
    return (unsigned short)(u >> 16);
}
__device__ __forceinline__ unsigned pk2(float a, float b) {
    return (unsigned)f2bf(a) | ((unsigned)f2bf(b) << 16);
}
__device__ __forceinline__ float bf2f(unsigned short s) {
    return __builtin_bit_cast(float, (unsigned)s << 16);
}
__device__ __forceinline__ void dec2(unsigned p, float& lo, float& hi) {
    lo = __builtin_bit_cast(float, p << 16);
    hi = __builtin_bit_cast(float, p & 0xffff0000u);
}

template <bool BN>
__device__ __forceinline__ void acc8(uint4 p, float* a, const float* sc, const float* sh) {
    float v[8];
    dec2(p.x, v[0], v[1]);
    dec2(p.y, v[2], v[3]);
    dec2(p.z, v[4], v[5]);
    dec2(p.w, v[6], v[7]);
#pragma unroll
    for (int j = 0; j < 8; ++j) {
        float t = BN ? fmaxf(fmaf(v[j], sc[j], sh[j]), 0.f) : v[j];
        a[j] += t;
    }
}

// ---------------- workspace zeroing (replaces 3 memsets: 1 graph node) ------

__global__ __launch_bounds__(256) void zero_kernel(int* __restrict__ deg,
                                                   float* __restrict__ csums,
                                                   float* __restrict__ csqs) {
    int i = blockIdx.x * blockDim.x + threadIdx.x;
    int stride = gridDim.x * blockDim.x;
    if (i < 3 * DIM) {
        csums[i] = 0.f;
        csqs[i] = 0.f;
    }
    for (; i < N_NODES; i += stride) deg[i] = 0;
}

// ---------------- CSR build ----------------

__global__ __launch_bounds__(256) void hist_kernel(const int* __restrict__ dst,
                                                   int* __restrict__ deg) {
    int i = blockIdx.x * blockDim.x + threadIdx.x;
    int stride = gridDim.x * blockDim.x;
    const int NE4 = N_EDGES / 4;
    for (; i < NE4; i += stride) {
        int4 d4 = ((const int4*)dst)[i];
        atomicAdd(&deg[d4.x], 1);
        atomicAdd(&deg[d4.y], 1);
        atomicAdd(&deg[d4.z], 1);
        atomicAdd(&deg[d4.w], 1);
    }
}

// fill partitioned by dst range: NPART=4 (R11: halves edge re-reads vs 8;
// 2 XCDs share a partition -> ~2x write-amp on 6.4 MB, net win)
__global__ __launch_bounds__(256) void fill_part_kernel(const int* __restrict__ src,
                                                        const int* __restrict__ dst,
                                                        int* __restrict__ cursor,
                                                        int* __restrict__ csr) {
    int p = blockIdx.x & (NPART - 1);
    int bgrp = blockIdx.x >> 2;
    int nb = gridDim.x >> 2;
    int tid = bgrp * blockDim.x + threadIdx.x;
    int nthreads = nb * blockDim.x;
    const int NE8 = N_EDGES / 8;
    for (int i = tid; i < NE8; i += nthreads) {
        int4 da = ((const int4*)dst)[2 * i];
        int4 db = ((const int4*)dst)[2 * i + 1];
        int4 sa = ((const int4*)src)[2 * i];
        int4 sb = ((const int4*)src)[2 * i + 1];
        if (da.x / PART_SZ == p) csr[atomicAdd(&cursor[da.x], 1)] = sa.x;
        if (da.y / PART_SZ == p) csr[atomicAdd(&cursor[da.y], 1)] = sa.y;
        if (da.z / PART_SZ == p) csr[atomicAdd(&cursor[da.z], 1)] = sa.z;
        if (da.w / PART_SZ == p) csr[atomicAdd(&cursor[da.w], 1)] = sa.w;
        if (db.x / PART_SZ == p) csr[atomicAdd(&cursor[db.x], 1)] = sb.x;
        if (db.y / PART_SZ == p) csr[atomicAdd(&cursor[db.y], 1)] = sb.y;
        if (db.z / PART_SZ == p) csr[atomicAdd(&cursor[db.z], 1)] = sb.z;
        if (db.w / PART_SZ == p) csr[atomicAdd(&cursor[db.w], 1)] = sb.w;
    }
}

// ---------------- hierarchical scan ----------------

__global__ __launch_bounds__(SCAN_BLOCK) void scan_partial_kernel(const int* __restrict__ deg,
                                                                  int* __restrict__ partials) {
    __shared__ int red[SCAN_BLOCK / 64];
    int i = blockIdx.x * SCAN_BLOCK + threadIdx.x;
    int v = (i < N_NODES) ? deg[i] : 0;
    for (int o = 32; o > 0; o >>= 1) v += __shfl_down(v, o, 64);
    if ((threadIdx.x & 63) == 0) red[threadIdx.x >> 6] = v;
    __syncthreads();
    if (threadIdx.x == 0) {
        int s = 0;
#pragma unroll
        for (int w = 0; w < SCAN_BLOCK / 64; ++w) s += red[w];
        partials[blockIdx.x] = s;
    }
}

__global__ __launch_bounds__(512) void scan_partials_kernel(int* __restrict__ partials,
                                                            int* __restrict__ off) {
    __shared__ int sm[512];
    int t = threadIdx.x;
    int v = (t < SCAN_NB) ? partials[t] : 0;
    sm[t] = v;
    __syncthreads();
    for (int o = 1; o < 512; o <<= 1) {
        int u = (t >= o) ? sm[t - o] : 0;
        __syncthreads();
        sm[t] += u;
        __syncthreads();
    }
    if (t < SCAN_NB) partials[t] = sm[t] - v;
    if (t == 0) off[N_NODES] = sm[511];
}

__global__ __launch_bounds__(SCAN_BLOCK) void scan_scatter_kernel(const int* __restrict__ deg,
                                                                  const int* __restrict__ partials,
                                                                  int* __restrict__ off,
                                                                  int* __restrict__ cursor) {
    __shared__ int sm[SCAN_BLOCK];
    int t = threadIdx.x;
    int i = blockIdx.x * SCAN_BLOCK + t;
    int v = (i < N_NODES) ? deg[i] : 0;
    sm[t] = v;
    __syncthreads();
    for (int o = 1; o < SCAN_BLOCK; o <<= 1) {
        int u = (t >= o) ? sm[t - o] : 0;
        __syncthreads();
        sm[t] += u;
        __syncthreads();
    }
    if (i < N_NODES) {
        int r = partials[blockIdx.x] + sm[t] - v;
        off[i] = r;
        cursor[i] = r;
    }
}

// ---------------- merged W-prep + x conversion (1 graph node) ----------------
// blocks 0..23: wb4[l][nt][kk][lane] B-fragment layout (verified R5)
// blocks 24.. : x f32 -> bf16, padded rows zeroed

__global__ __launch_bounds__(256) void prep_kernel(const float* __restrict__ W1,
                                                   const float* __restrict__ W2,
                                                   const float* __restrict__ W3,
                                                   uint4* __restrict__ wb4,
                                                   const float* __restrict__ x,
                                                   unsigned short* __restrict__ xb) {
    if (blockIdx.x < 24) {
        int t = blockIdx.x * 256 + threadIdx.x;  // 0..6143
        int b = t >> 6;                          // 0..95: l*32 + nt*4 + kk
        int lane = t & 63;
        int l = b >> 5;
        int nt = (b >> 2) & 7;
        int kk = b & 3;
        const float* W = (l == 0) ? W1 : (l == 1) ? W2 : W3;
        int row = nt * 16 + (lane & 15);
        int cb = kk * 32 + (lane >> 4) * 8;
        const float* g = W + row * DIM + cb;
        float4 f0 = *(const float4*)g;
        float4 f1 = *(const float4*)(g + 4);
        uint4 o;
        o.x = pk2(f0.x, f0.y);
        o.y = pk2(f0.z, f0.w);
        o.z = pk2(f1.x, f1.y);
        o.w = pk2(f1.z, f1.w);
        wb4[(size_t)b * 64 + lane] = o;
        return;
    }
    int i = (blockIdx.x - 24) * blockDim.x + threadIdx.x;
    int stride = (gridDim.x - 24) * blockDim.x;
    const int TOT = N_PAD * DIM / 8;
    for (; i < TOT; i += stride) {
        int row = i >> 4;
        int ks = i & 15;
        uint4 o = {0, 0, 0, 0};
        if (row < N_NODES) {
            const float* g = x + (size_t)row * DIM + ks * 8;
            float4 f0 = *(const float4*)g;
            float4 f1 = *(const float4*)(g + 4);
            o.x = pk2(f0.x, f0.y);
            o.y = pk2(f0.z, f0.w);
            o.z = pk2(f1.x, f1.y);
            o.w = pk2(f1.z, f1.w);
        }
        ((uint4*)xb)[i] = o;
    }
}

// ---------------- fused agg + MFMA GEMM (R9 config, verified 103 us) --------
// 64-row tile, wave-per-row gather (zero divergence), 2x 1KB gathers in
// flight. R10 falsified "more concurrency helps": gather plateaus ~1.8 TB/s
// L2-miss traffic regardless of ILP/occupancy. This config sits on it.

template <bool BN>
__global__ __launch_bounds__(256) void agg_gemm_kernel(const unsigned short* __restrict__ hin,
                                                       const int* __restrict__ off,
                                                       const int* __restrict__ csr,
                                                       const float* __restrict__ eps_arr, int layer,
                                                       const float* __restrict__ csum_prev,
                                                       const float* __restrict__ csq_prev,
                                                       const float* __restrict__ gamma_prev,
                                                       const float* __restrict__ beta_prev,
                                                       const uint4* __restrict__ wb4,
                                                       unsigned short* __restrict__ y,
                                                       float* __restrict__ csum_out,
                                                       float* __restrict__ csq_out) {
    __shared__ unsigned short tile[64 * DIM];  // bf16, 16B-granular XOR swizzle
    __shared__ float sstat[4][DIM];
    __shared__ float sstatq[4][DIM];
    int tid = threadIdx.x;
    int row0 = blockIdx.x * 64;
    int wv = tid >> 6;          // wave 0..3, owns rows wv*16 .. wv*16+15
    int esl = (tid >> 4) & 3;   // edge slot within wave
    int dl = tid & 15;          // dim lane: dims dl*8 .. dl*8+7
    float se = 1.0f + eps_arr[layer];
    float sc[8], sh[8];
    if (BN) {
#pragma unroll
        for (int j = 0; j < 8; ++j) {
            int d = dl * 8 + j;
            float m = csum_prev[d] * (1.0f / N_NODES);
            float var = csq_prev[d] * (1.0f / N_NODES) - m * m;
            float s = gamma_prev[d] * rsqrtf(var + 1e-5f);
            sc[j] = s;
            sh[j] = beta_prev[d] - m * s;
        }
    }
    const uint4* base = (const uint4*)hin + dl;
    const size_t RS = DIM / 8;  // uint4 per row

#pragma unroll 1
    for (int r = 0; r < 16; ++r) {
        int trow = wv * 16 + r;
        int row = row0 + trow;
        float a[8] = {0.f, 0.f, 0.f, 0.f, 0.f, 0.f, 0.f, 0.f};
        float s8[8] = {0.f, 0.f, 0.f, 0.f, 0.f, 0.f, 0.f, 0.f};
        if (row < N_NODES) {
            {   // self term (all lanes; 4-slot broadcast of 256B row)
                uint4 pv = base[(size_t)row * RS];
                float v[8];
                dec2(pv.x, v[0], v[1]); dec2(pv.y, v[2], v[3]);
                dec2(pv.z, v[4], v[5]); dec2(pv.w, v[6], v[7]);
#pragma unroll
                for (int j = 0; j < 8; ++j)
                    s8[j] = BN ? fmaxf(fmaf(v[j], sc[j], sh[j]), 0.f) : v[j];
            }
            int k = off[row], e = off[row + 1];
            // main: 8 edges per trip, 2 gathers in flight per lane
            for (; k + 8 <= e; k += 8) {
                int i0 = csr[k + esl];
                int i1 = csr[k + 4 + esl];
                uint4 p0 = base[(size_t)i0 * RS];
                uint4 p1 = base[(size_t)i1 * RS];
                acc8<BN>(p0, a, sc, sh);
                acc8<BN>(p1, a, sc, sh);
            }
            // tail: predicated quads
            for (; k < e; k += 4) {
                int kk = k + esl;
                if (kk < e) {
                    uint4 p0 = base[(size_t)csr[kk] * RS];
                    acc8<BN>(p0, a, sc, sh);
                }
            }
        }
        // combine the 4 edge-slots (butterfly over lane bits 4,5)
#pragma unroll
        for (int j = 0; j < 8; ++j) {
            a[j] += __shfl_xor(a[j], 16);
            a[j] += __shfl_xor(a[j], 32);
            a[j] = fmaf(se, s8[j], a[j]);
        }
        if (esl == 0) {
            uint4 pw;
            pw.x = pk2(a[0], a[1]);
            pw.y = pk2(a[2], a[3]);
            pw.z = pk2(a[4], a[5]);
            pw.w = pk2(a[6], a[7]);
            int byte = (trow * 256 + dl * 16) ^ ((trow & 7) << 4);
            *(uint4*)((char*)tile + byte) = pw;
        }
    }
    __syncthreads();

    // ---- MFMA phase (layout verified R5) ----
    int w = tid >> 6;
    int l = tid & 63;
    int lr = l & 15;
    int lg = l >> 4;
    bf16x8 a[4];
#pragma unroll
    for (int kk = 0; kk < 4; ++kk) {
        int row = w * 16 + lr;
        int byte = (row * 256 + kk * 64 + lg * 16) ^ ((row & 7) << 4);
        a[kk] = __builtin_bit_cast(bf16x8, *(uint4*)((char*)tile + byte));
    }

#pragma unroll
    for (int nt = 0; nt < 8; ++nt) {
        f32x4 acc = {0.0f, 0.0f, 0.0f, 0.0f};
#pragma unroll
        for (int kk = 0; kk < 4; ++kk) {
            bf16x8 b = __builtin_bit_cast(bf16x8, wb4[(nt * 4 + kk) * 64 + l]);
            acc = __builtin_amdgcn_mfma_f32_16x16x32_bf16(a[kk], b, acc, 0, 0, 0);
        }
        int col = nt * 16 + lr;
        size_t base2 = (size_t)(row0 + w * 16 + lg * 4) * DIM + col;
        y[base2] = f2bf(acc[0]);
        y[base2 + DIM] = f2bf(acc[1]);
        y[base2 + 2 * DIM] = f2bf(acc[2]);
        y[base2 + 3 * DIM] = f2bf(acc[3]);
        float s = acc[0] + acc[1] + acc[2] + acc[3];
        float q = acc[0] * acc[0] + acc[1] * acc[1] + acc[2] * acc[2] + acc[3] * acc[3];
        s += __shfl_xor(s, 16);
        s += __shfl_xor(s, 32);
        q += __shfl_xor(q, 16);
        q += __shfl_xor(q, 32);
        if (lg == 0) {
            sstat[w][col] = s;
            sstatq[w][col] = q;
        }
    }
    __syncthreads();
    if (tid < DIM) {
        float s = sstat[0][tid] + sstat[1][tid] + sstat[2][tid] + sstat[3][tid];
        float q = sstatq[0][tid] + sstatq[1][tid] + sstatq[2][tid] + sstatq[3][tid];
        atomicAdd(&csum_out[tid], s);
        atomicAdd(&csq_out[tid], q);
    }
}

// ---------------- global mean pool (final BN+ReLU inline) ----------------

__global__ __launch_bounds__(128) void pool_kernel(const unsigned short* __restrict__ y,
                                                   const int* __restrict__ batch,
                                                   const float* __restrict__ csum,
                                                   const float* __restrict__ csq,
                                                   const float* __restrict__ gamma,
                                                   const float* __restrict__ beta,
                                                   float* __restrict__ out) {
    int gph = blockIdx.x;
    int d = threadIdx.x;
    float m = csum[d] * (1.0f / N_NODES);
    float var = csq[d] * (1.0f / N_NODES) - m * m;
    float sc = gamma[d] * rsqrtf(var + 1e-5f);
    float sh = beta[d] - m * sc;
    int lo = 0, hi = N_NODES;
    while (lo < hi) {
        int mid = (lo + hi) >> 1;
        if (batch[mid] < gph) lo = mid + 1; else hi = mid;
    }
    int start = lo;
    hi = N_NODES;
    while (lo < hi) {
        int mid = (lo + hi) >> 1;
        if (batch[mid] < gph + 1) lo = mid + 1; else hi = mid;
    }
    int end = lo;
    float s0 = 0.f, s1 = 0.f, s2 = 0.f, s3 = 0.f;
    int n = start;
    for (; n + 3 < end; n += 4) {
        float v0 = bf2f(y[(size_t)n * DIM + d]);
        float v1 = bf2f(y[(size_t)(n + 1) * DIM + d]);
        float v2 = bf2f(y[(size_t)(n + 2) * DIM + d]);
        float v3 = bf2f(y[(size_t)(n + 3) * DIM + d]);
        s0 += fmaxf(fmaf(v0, sc, sh), 0.0f);
        s1 += fmaxf(fmaf(v1, sc, sh), 0.0f);
        s2 += fmaxf(fmaf(v2, sc, sh), 0.0f);
        s3 += fmaxf(fmaf(v3, sc, sh), 0.0f);
    }
    for (; n < end; ++n) {
        float v = bf2f(y[(size_t)n * DIM + d]);
        s0 += fmaxf(fmaf(v, sc, sh), 0.0f);
    }
    float s = (s0 + s1) + (s2 + s3);
    out[gph * DIM + d] = s / fmaxf((float)(end - start), 1.0f);
}

// ---------------- launch ----------------

extern "C" void kernel_launch(void* const* d_in, const int* in_sizes, int n_in,
                              void* d_out, int out_size, void* d_ws, size_t ws_size,
                              hipStream_t stream) {
    const float* x = (const float*)d_in[0];
    const int* ei = (const int*)d_in[1];
    const int* batch = (const int*)d_in[2];
    const float* Wp[3] = {(const float*)d_in[3], (const float*)d_in[5], (const float*)d_in[7]};
    const float* eps = (const float*)d_in[9];
    const float* gamma = (const float*)d_in[10];
    const float* beta = (const float*)d_in[11];
    float* out = (float*)d_out;

    char* ws = (char*)d_ws;
    size_t o = 0;
    auto alloc = [&](size_t bytes) {
        void* p = ws + o;
        o = (o + bytes + 255) & ~(size_t)255;
        return p;
    };
    int* deg = (int*)alloc(N_NODES * sizeof(int));
    int* off = (int*)alloc((N_NODES + 1) * sizeof(int));
    int* cursor = (int*)alloc(N_NODES * sizeof(int));
    int* partials = (int*)alloc(SCAN_NB * sizeof(int));
    int* csr = (int*)alloc(N_EDGES * sizeof(int));
    uint4* wb4 = (uint4*)alloc(3 * 8 * 4 * 64 * 16);
    float* csums = (float*)alloc(3 * DIM * sizeof(float));
    float* csqs = (float*)alloc(3 * DIM * sizeof(float));
    unsigned short* xb = (unsigned short*)alloc((size_t)N_PAD * DIM * 2);
    unsigned short* y0 = (unsigned short*)alloc((size_t)N_PAD * DIM * 2);
    unsigned short* y1 = (unsigned short*)alloc((size_t)N_PAD * DIM * 2);

    zero_kernel<<<256, 256, 0, stream>>>(deg, csums, csqs);
    hist_kernel<<<1024, 256, 0, stream>>>(ei + N_EDGES, deg);
    scan_partial_kernel<<<SCAN_NB, SCAN_BLOCK, 0, stream>>>(deg, partials);
    scan_partials_kernel<<<1, 512, 0, stream>>>(partials, off);
    scan_scatter_kernel<<<SCAN_NB, SCAN_BLOCK, 0, stream>>>(deg, partials, off, cursor);
    fill_part_kernel<<<2048, 256, 0, stream>>>(ei, ei + N_EDGES, cursor, csr);
    prep_kernel<<<24 + 2048, 256, 0, stream>>>(Wp[0], Wp[1], Wp[2], wb4, x, xb);

    const int NBLK = N_PAD / 64;  // 1563
    agg_gemm_kernel<false><<<NBLK, 256, 0, stream>>>(xb, off, csr, eps, 0,
                                                     nullptr, nullptr, nullptr, nullptr,
                                                     wb4, y0, csums, csqs);
    agg_gemm_kernel<true><<<NBLK, 256, 0, stream>>>(y0, off, csr, eps, 1,
                                                    csums, csqs, gamma, beta,
                                                    wb4 + 2048, y1, csums + DIM, csqs + DIM);
    agg_gemm_kernel<true><<<NBLK, 256, 0, stream>>>(y1, off, csr, eps, 2,
                                                    csums + DIM, csqs + DIM, gamma + DIM, beta + DIM,
                                                    wb4 + 4096, y0, csums + 2 * DIM, csqs + 2 * DIM);
    pool_kernel<<<N_GRAPHS, DIM, 0, stream>>>(y0, batch, csums + 2 * DIM, csqs + 2 * DIM,
                                              gamma + 2 * DIM, beta + 2 * DIM, out);
}